// Round 1
// baseline (624.545 us; speedup 1.0000x reference)
//
#include <hip/hip_runtime.h>
#include <math.h>

#define BB 512
#define SS 16384
#define LOG2S 14
#define TPI_D 6.283185307179586476925286766559

// ---------------------------------------------------------------------------
// Shared FFT helpers (in-place radix-2 DIT on LDS arrays, length SS=16384)
// ---------------------------------------------------------------------------
__device__ __forceinline__ void bitrev_lds(float* re, float* im, int tid, int nth) {
    for (int n = tid; n < SS; n += nth) {
        int r = (int)(__brev((unsigned)n) >> (32 - LOG2S));
        if (r > n) {
            float t;
            t = re[n]; re[n] = re[r]; re[r] = t;
            t = im[n]; im[n] = im[r]; im[r] = t;
        }
    }
    __syncthreads();
}

__device__ __forceinline__ void fft_stages(float* re, float* im, int tid, int nth, float sgn) {
    for (int s = 1; s <= LOG2S; ++s) {
        const int half = 1 << (s - 1);
        for (int b = tid; b < (SS >> 1); b += nth) {
            int pos = b & (half - 1);
            int i0 = ((b >> (s - 1)) << s) + pos;
            int i1 = i0 + half;
            float ang = sgn * (float)(TPI_D * (double)pos / (double)(1 << s));
            float cw, sw;
            sincosf(ang, &sw, &cw);
            float ar = re[i0], ai = im[i0];
            float br = re[i1], bi = im[i1];
            float tr = br * cw - bi * sw;
            float ti = br * sw + bi * cw;
            re[i0] = ar + tr; im[i0] = ai + ti;
            re[i1] = ar - tr; im[i1] = ai - ti;
        }
        __syncthreads();
    }
}

// ---------------------------------------------------------------------------
// K1: per-row Pearson (1 - pear). Global standardization is affine-global ->
// Pearson is exactly invariant, so compute from raw data in fp64.
// ---------------------------------------------------------------------------
__global__ __launch_bounds__(256) void k_pearson(const float* __restrict__ pred,
                                                 const float* __restrict__ targ,
                                                 const int* __restrict__ ip,
                                                 float* __restrict__ out1m) {
    __shared__ double sred[256];
    const int row = blockIdx.x;
    const int tid = threadIdx.x;
    const float* x = pred + (size_t)ip[0] * (size_t)BB * SS + (size_t)row * SS;
    const float* y = targ + (size_t)row * SS;
    double sx = 0, sy = 0, sxy = 0, sxx = 0, syy = 0;
    for (int n = tid; n < SS; n += 256) {
        double a = x[n], b = y[n];
        sx += a; sy += b; sxy += a * b; sxx += a * a; syy += b * b;
    }
    double vals[5] = {sx, sy, sxy, sxx, syy};
    for (int q = 0; q < 5; ++q) {
        sred[tid] = vals[q]; __syncthreads();
        for (int s = 128; s > 0; s >>= 1) {
            if (tid < s) sred[tid] += sred[tid + s];
            __syncthreads();
        }
        vals[q] = sred[0]; __syncthreads();
    }
    if (tid == 0) {
        double N = (double)SS;
        double num = N * vals[2] - vals[0] * vals[1];
        double den = sqrt((N * vals[3] - vals[0] * vals[0]) * (N * vals[4] - vals[1] * vals[1]));
        out1m[row] = (float)(1.0 - num / den);
    }
}

// ---------------------------------------------------------------------------
// K2: phase-only correlation. z = hann*x + i*hann*y; FFT; unpack Hermitian;
// C = X*conj(Y)/|.|; rebuild full spectrum; inverse FFT; argmax(Re);
// out = cos(2*pi*idx/N).
// ---------------------------------------------------------------------------
__global__ __launch_bounds__(1024) void k_phase(const float* __restrict__ pred,
                                                const float* __restrict__ targ,
                                                const int* __restrict__ ip,
                                                float* __restrict__ outcos) {
    __shared__ float re[SS];
    __shared__ float im[SS];
    __shared__ float sval[1024];
    __shared__ int   sidx[1024];
    const int row = blockIdx.x;
    const int tid = threadIdx.x;
    const float* x = pred + (size_t)ip[0] * (size_t)BB * SS + (size_t)row * SS;
    const float* y = targ + (size_t)row * SS;
    for (int n = tid; n < SS; n += 1024) {
        float ang = (6.28318530717958647692f * (float)n) / (float)SS;
        float w = 0.5f * (1.0f - cosf(ang));   // periodic hann, fp32 like jnp
        re[n] = x[n] * w;
        im[n] = y[n] * w;
    }
    __syncthreads();
    bitrev_lds(re, im, tid, 1024);
    fft_stages(re, im, tid, 1024, -1.0f);
    // unpack packed real FFTs, phase-normalize cross-spectrum, write Hermitian C
    for (int k = tid; k <= SS / 2; k += 1024) {
        int m = (SS - k) & (SS - 1);
        float a = re[k], b = im[k];
        float c = re[m], d = im[m];
        float xr = 0.5f * (a + c), xi = 0.5f * (b - d);   // X[k]
        float yr = 0.5f * (b + d), yi = 0.5f * (c - a);   // Y[k]
        float cr = xr * yr + xi * yi;                     // X * conj(Y)
        float ci = xi * yr - xr * yi;
        float mag = sqrtf(cr * cr + ci * ci);
        cr /= mag; ci /= mag;
        re[k] = cr; im[k] = ci;
        re[m] = cr; im[m] = -ci;
    }
    __syncthreads();
    bitrev_lds(re, im, tid, 1024);
    fft_stages(re, im, tid, 1024, 1.0f);   // inverse (1/N scale dropped: argmax-invariant)
    // argmax of real part, first-index tie-break
    float best = -1e30f; int bidx = 0;
    for (int n = tid; n < SS; n += 1024) {
        float v = re[n];
        if (v > best) { best = v; bidx = n; }
    }
    sval[tid] = best; sidx[tid] = bidx;
    __syncthreads();
    for (int s = 512; s > 0; s >>= 1) {
        if (tid < s) {
            float v2 = sval[tid + s]; int i2 = sidx[tid + s];
            if (v2 > sval[tid] || (v2 == sval[tid] && i2 < sidx[tid])) {
                sval[tid] = v2; sidx[tid] = i2;
            }
        }
        __syncthreads();
    }
    if (tid == 0) {
        float ang = (6.28318530717958647692f * (float)sidx[0]) / (float)SS;
        outcos[row] = cosf(ang);
    }
}

// ---------------------------------------------------------------------------
// K3: power spectrum. z = x + i*y (no window); FFT; per rfft bin accumulate
// |xp - tp| and tp in fp64.
// ---------------------------------------------------------------------------
__global__ __launch_bounds__(1024) void k_power(const float* __restrict__ pred,
                                                const float* __restrict__ targ,
                                                const int* __restrict__ ip,
                                                double* __restrict__ onum,
                                                double* __restrict__ oden) {
    __shared__ float re[SS];
    __shared__ float im[SS];
    __shared__ double dred[1024];
    const int row = blockIdx.x;
    const int tid = threadIdx.x;
    const float* x = pred + (size_t)ip[0] * (size_t)BB * SS + (size_t)row * SS;
    const float* y = targ + (size_t)row * SS;
    for (int n = tid; n < SS; n += 1024) { re[n] = x[n]; im[n] = y[n]; }
    __syncthreads();
    bitrev_lds(re, im, tid, 1024);
    fft_stages(re, im, tid, 1024, -1.0f);
    double anum = 0.0, aden = 0.0;
    for (int k = tid; k <= SS / 2; k += 1024) {
        int m = (SS - k) & (SS - 1);
        float a = re[k], b = im[k];
        float c = re[m], d = im[m];
        float xr = 0.5f * (a + c), xi = 0.5f * (b - d);
        float yr = 0.5f * (b + d), yi = 0.5f * (c - a);
        float xa = sqrtf(xr * xr + xi * xi); float xp = xa * xa;  // abs()**2 like jnp
        float ya = sqrtf(yr * yr + yi * yi); float tp = ya * ya;
        anum += (double)fabsf(xp - tp);
        aden += (double)tp;
    }
    __syncthreads();
    dred[tid] = anum; __syncthreads();
    for (int s = 512; s > 0; s >>= 1) { if (tid < s) dred[tid] += dred[tid + s]; __syncthreads(); }
    if (tid == 0) onum[row] = dred[0];
    __syncthreads();
    dred[tid] = aden; __syncthreads();
    for (int s = 512; s > 0; s >>= 1) { if (tid < s) dred[tid] += dred[tid + s]; __syncthreads(); }
    if (tid == 0) oden[row] = dred[0];
}

// ---------------------------------------------------------------------------
// K4: mutual information per row (10x10 hist, B*S denominator per reference)
// ---------------------------------------------------------------------------
__global__ __launch_bounds__(256) void k_mi(const float* __restrict__ pred,
                                            const float* __restrict__ targ,
                                            const int* __restrict__ ip,
                                            float* __restrict__ onmi) {
    __shared__ float fred[256];
    __shared__ int hist[100];
    __shared__ float hx[10], hy[10];
    __shared__ float bounds[4];  // xmin,xmax,ymin,ymax
    const int row = blockIdx.x;
    const int tid = threadIdx.x;
    const float* x = pred + (size_t)ip[0] * (size_t)BB * SS + (size_t)row * SS;
    const float* y = targ + (size_t)row * SS;
    float xmn = 1e30f, xmx = -1e30f, ymn = 1e30f, ymx = -1e30f;
    for (int n = tid; n < SS; n += 256) {
        float a = x[n], b = y[n];
        xmn = fminf(xmn, a); xmx = fmaxf(xmx, a);
        ymn = fminf(ymn, b); ymx = fmaxf(ymx, b);
    }
    fred[tid] = xmn; __syncthreads();
    for (int s = 128; s > 0; s >>= 1) { if (tid < s) fred[tid] = fminf(fred[tid], fred[tid + s]); __syncthreads(); }
    if (tid == 0) bounds[0] = fred[0]; __syncthreads();
    fred[tid] = xmx; __syncthreads();
    for (int s = 128; s > 0; s >>= 1) { if (tid < s) fred[tid] = fmaxf(fred[tid], fred[tid + s]); __syncthreads(); }
    if (tid == 0) bounds[1] = fred[0]; __syncthreads();
    fred[tid] = ymn; __syncthreads();
    for (int s = 128; s > 0; s >>= 1) { if (tid < s) fred[tid] = fminf(fred[tid], fred[tid + s]); __syncthreads(); }
    if (tid == 0) bounds[2] = fred[0]; __syncthreads();
    fred[tid] = ymx; __syncthreads();
    for (int s = 128; s > 0; s >>= 1) { if (tid < s) fred[tid] = fmaxf(fred[tid], fred[tid + s]); __syncthreads(); }
    if (tid == 0) bounds[3] = fred[0]; __syncthreads();

    float bwx = (bounds[1] - bounds[0]) / 10.0f;
    float bwy = (bounds[3] - bounds[2]) / 10.0f;
    if (tid < 100) hist[tid] = 0;
    __syncthreads();
    for (int n = tid; n < SS; n += 256) {
        float a = x[n], b = y[n];
        int ix = (int)((a - bounds[0]) / bwx); ix = min(max(ix, 0), 9);
        int iy = (int)((b - bounds[2]) / bwy); iy = min(max(iy, 0), 9);
        atomicAdd(&hist[ix * 10 + iy], 1);
    }
    __syncthreads();
    if (tid < 10) {
        int s1 = 0, s2 = 0;
        for (int j = 0; j < 10; ++j) { s1 += hist[tid * 10 + j]; s2 += hist[j * 10 + tid]; }
        hx[tid] = (float)s1; hy[tid] = (float)s2;
    }
    __syncthreads();
    const float denom = 8388608.0f;  // B*S, faithful to the reference
    const float eps = 1e-8f;
    float term = 0.0f;
    if (tid < 100) {
        int i = tid / 10, j = tid % 10;
        float pxy = (float)hist[tid] / denom;
        float px = hx[i] / denom, py = hy[j] / denom;
        term = pxy * logf((pxy + eps) / (px * py + eps));
    }
    fred[tid] = term; __syncthreads();
    for (int s = 128; s > 0; s >>= 1) { if (tid < s) fred[tid] += fred[tid + s]; __syncthreads(); }
    float mi = fred[0]; __syncthreads();

    float e = 0.0f;
    if (tid < 10) { float px = hx[tid] / denom; e = -px * logf(px + eps); }
    fred[tid] = e; __syncthreads();
    for (int s = 128; s > 0; s >>= 1) { if (tid < s) fred[tid] += fred[tid + s]; __syncthreads(); }
    float hxe = fred[0]; __syncthreads();

    e = 0.0f;
    if (tid < 10) { float py = hy[tid] / denom; e = -py * logf(py + eps); }
    fred[tid] = e; __syncthreads();
    for (int s = 128; s > 0; s >>= 1) { if (tid < s) fred[tid] += fred[tid + s]; __syncthreads(); }
    float hye = fred[0]; __syncthreads();

    if (tid == 0) onmi[row] = mi / (0.5f * (hxe + hye));
}

// ---------------------------------------------------------------------------
// K5: final combine (reads epoch on-device; graph-safe)
// ---------------------------------------------------------------------------
__global__ __launch_bounds__(512) void k_combine(const float* __restrict__ wpear,
                                                 const float* __restrict__ wpc,
                                                 const double* __restrict__ wnum,
                                                 const double* __restrict__ wden,
                                                 const float* __restrict__ wnmi,
                                                 const int* __restrict__ ep,
                                                 float* __restrict__ out) {
    __shared__ double dred[512];
    const int tid = threadIdx.x;
    double sums[5];
    double v[5] = {(double)wpear[tid], (double)wpc[tid], wnum[tid], wden[tid], (double)wnmi[tid]};
    for (int q = 0; q < 5; ++q) {
        dred[tid] = v[q]; __syncthreads();
        for (int s = 256; s > 0; s >>= 1) { if (tid < s) dred[tid] += dred[tid + s]; __syncthreads(); }
        sums[q] = dred[0]; __syncthreads();
    }
    if (tid == 0) {
        int epoch = ep[0];
        double loss = sums[0] / 512.0;                 // neg_pearson
        if (epoch >= 400) {
            loss += 1.0 - sums[1] / 512.0;             // phase correlation
            loss += sums[2] / sums[3];                 // power spectrum
        }
        if (epoch >= 700) {
            loss += 1.0 - sums[4] / 512.0;             // mutual information
        }
        out[0] = (float)loss;
    }
}

// ---------------------------------------------------------------------------
extern "C" void kernel_launch(void* const* d_in, const int* in_sizes, int n_in,
                              void* d_out, int out_size, void* d_ws, size_t ws_size,
                              hipStream_t stream) {
    const float* pred = (const float*)d_in[0];   // [2, 512, 16384] f32
    const float* targ = (const float*)d_in[1];   // [512, 16384] f32
    const int* ip = (const int*)d_in[2];         // scalar i
    const int* ep = (const int*)d_in[3];         // scalar epoch
    float* out = (float*)d_out;

    double* wnum = (double*)d_ws;                // [512]
    double* wden = wnum + BB;                    // [512]
    float* wpear = (float*)(wden + BB);          // [512]
    float* wpc = wpear + BB;                     // [512]
    float* wnmi = wpc + BB;                      // [512]

    k_pearson<<<dim3(BB), dim3(256), 0, stream>>>(pred, targ, ip, wpear);
    k_phase<<<dim3(BB), dim3(1024), 0, stream>>>(pred, targ, ip, wpc);
    k_power<<<dim3(BB), dim3(1024), 0, stream>>>(pred, targ, ip, wnum, wden);
    k_mi<<<dim3(BB), dim3(256), 0, stream>>>(pred, targ, ip, wnmi);
    k_combine<<<dim3(1), dim3(512), 0, stream>>>(wpear, wpc, wnum, wden, wnmi, ep, out);
}

// Round 2
// 346.591 us; speedup vs baseline: 1.8020x; 1.8020x over previous
//
#include <hip/hip_runtime.h>
#include <math.h>

#define BB 512
#define SS 16384
#define LOG2S 14

// LDS layout: interleaved complex float2, padded every 16 elements (128 B)
// so radix-4 strides 4/16/64 all hit optimal 4-way bank aliasing for b64 ops.
#define IDX(i) ((i) + ((i) >> 4))
#define PADDED (SS + (SS >> 4))   // 17408 float2 = 139264 B

// ---------------------------------------------------------------------------
// base-4 digit reversal of a 14-bit index (7 digits):
// full bit-reverse, then swap adjacent bit pairs.
// ---------------------------------------------------------------------------
__device__ __forceinline__ int digrev4(int n) {
    unsigned x = __brev((unsigned)n) >> (32 - LOG2S);
    return (int)(((x & 0x1555u) << 1) | ((x >> 1) & 0x1555u));
}

__device__ __forceinline__ void digrev_lds(float2* cd, int tid) {
    for (int n = tid; n < SS; n += 1024) {
        int r = digrev4(n);
        if (r > n) {
            float2 t = cd[IDX(n)];
            cd[IDX(n)] = cd[IDX(r)];
            cd[IDX(r)] = t;
        }
    }
    __syncthreads();
}

// ---------------------------------------------------------------------------
// In-place radix-4 DIT FFT, N=16384, 7 stages. SGN=-1 forward, +1 inverse.
// Twiddle W_L^p via hw v_sin/v_cos (input in REVOLUTIONS); W^2p, W^3p by
// complex-multiply chain. One transcendental pair per butterfly.
// ---------------------------------------------------------------------------
template <int SGN>
__device__ __forceinline__ void fft4(float2* cd, int tid) {
    const float sg = (float)SGN;
    for (int s = 0; s < 7; ++s) {
        const int Q = 1 << (2 * s);
        const float tw = sg / (float)(Q << 2);
        for (int b = tid; b < (SS >> 2); b += 1024) {
            const int p = b & (Q - 1);
            const int i0 = ((b >> (2 * s)) << (2 * s + 2)) + p;
            const int i1 = i0 + Q, i2 = i1 + Q, i3 = i2 + Q;
            const float rev = tw * (float)p;                 // in [-0.25, 0.25]
            const float c1 = __builtin_amdgcn_cosf(rev);
            const float s1 = __builtin_amdgcn_sinf(rev);
            const float c2 = c1 * c1 - s1 * s1, s2 = 2.0f * c1 * s1;
            const float c3 = c1 * c2 - s1 * s2, s3 = c1 * s2 + s1 * c2;
            float2 A0 = cd[IDX(i0)], A1 = cd[IDX(i1)], A2 = cd[IDX(i2)], A3 = cd[IDX(i3)];
            float a1r = A1.x * c1 - A1.y * s1, a1i = A1.x * s1 + A1.y * c1;
            float a2r = A2.x * c2 - A2.y * s2, a2i = A2.x * s2 + A2.y * c2;
            float a3r = A3.x * c3 - A3.y * s3, a3i = A3.x * s3 + A3.y * c3;
            float t0r = A0.x + a2r, t0i = A0.y + a2i;
            float t1r = A0.x - a2r, t1i = A0.y - a2i;
            float t2r = a1r + a3r, t2i = a1i + a3i;
            float t3r = a1r - a3r, t3i = a1i - a3i;
            cd[IDX(i0)] = make_float2(t0r + t2r, t0i + t2i);
            cd[IDX(i2)] = make_float2(t0r - t2r, t0i - t2i);
            cd[IDX(i1)] = make_float2(t1r - sg * t3i, t1i + sg * t3r);
            cd[IDX(i3)] = make_float2(t1r + sg * t3i, t1i - sg * t3r);
        }
        __syncthreads();
    }
}

// ---------------------------------------------------------------------------
// K1: per-row Pearson (1 - pear). Global standardization is affine-global ->
// Pearson is exactly invariant, so compute from raw data in fp64.
// ---------------------------------------------------------------------------
__global__ __launch_bounds__(256) void k_pearson(const float* __restrict__ pred,
                                                 const float* __restrict__ targ,
                                                 const int* __restrict__ ip,
                                                 float* __restrict__ out1m) {
    __shared__ double sred[256];
    const int row = blockIdx.x;
    const int tid = threadIdx.x;
    const float* x = pred + (size_t)ip[0] * (size_t)BB * SS + (size_t)row * SS;
    const float* y = targ + (size_t)row * SS;
    double sx = 0, sy = 0, sxy = 0, sxx = 0, syy = 0;
    for (int n = tid; n < SS; n += 256) {
        double a = x[n], b = y[n];
        sx += a; sy += b; sxy += a * b; sxx += a * a; syy += b * b;
    }
    double vals[5] = {sx, sy, sxy, sxx, syy};
    for (int q = 0; q < 5; ++q) {
        sred[tid] = vals[q]; __syncthreads();
        for (int s = 128; s > 0; s >>= 1) {
            if (tid < s) sred[tid] += sred[tid + s];
            __syncthreads();
        }
        vals[q] = sred[0]; __syncthreads();
    }
    if (tid == 0) {
        double N = (double)SS;
        double num = N * vals[2] - vals[0] * vals[1];
        double den = sqrt((N * vals[3] - vals[0] * vals[0]) * (N * vals[4] - vals[1] * vals[1]));
        out1m[row] = (float)(1.0 - num / den);
    }
}

// ---------------------------------------------------------------------------
// K2: phase-only correlation. z = hann*x + i*hann*y; FFT; unpack Hermitian;
// C = X*conj(Y)/|.|; rebuild full spectrum; inverse FFT; argmax(Re);
// out = cos(2*pi*idx/N). (1/N irfft scale dropped: argmax-invariant.)
// ---------------------------------------------------------------------------
__global__ __launch_bounds__(1024) void k_phase(const float* __restrict__ pred,
                                                const float* __restrict__ targ,
                                                const int* __restrict__ ip,
                                                float* __restrict__ outcos) {
    __shared__ float2 cd[PADDED];
    __shared__ float sval[1024];
    __shared__ int   sidx[1024];
    const int row = blockIdx.x;
    const int tid = threadIdx.x;
    const float* x = pred + (size_t)ip[0] * (size_t)BB * SS + (size_t)row * SS;
    const float* y = targ + (size_t)row * SS;
    for (int n = tid; n < SS; n += 1024) {
        // periodic hann: 0.5*(1 - cos(2*pi*n/N)); hw cos takes revolutions
        float w = 0.5f * (1.0f - __builtin_amdgcn_cosf((float)n * (1.0f / (float)SS)));
        cd[IDX(n)] = make_float2(x[n] * w, y[n] * w);
    }
    __syncthreads();
    digrev_lds(cd, tid);
    fft4<-1>(cd, tid);
    // unpack packed real FFTs, phase-normalize cross-spectrum, write Hermitian C
    for (int k = tid; k <= SS / 2; k += 1024) {
        int m = (SS - k) & (SS - 1);
        float2 Zk = cd[IDX(k)], Zm = cd[IDX(m)];
        float xr = 0.5f * (Zk.x + Zm.x), xi = 0.5f * (Zk.y - Zm.y);   // X[k]
        float yr = 0.5f * (Zk.y + Zm.y), yi = 0.5f * (Zm.x - Zk.x);   // Y[k]
        float cr = xr * yr + xi * yi;                                  // X * conj(Y)
        float ci = xi * yr - xr * yi;
        float mag = sqrtf(cr * cr + ci * ci);
        cr /= mag; ci /= mag;
        cd[IDX(k)] = make_float2(cr, ci);
        cd[IDX(m)] = make_float2(cr, -ci);
    }
    __syncthreads();
    digrev_lds(cd, tid);
    fft4<1>(cd, tid);
    // argmax of real part, first-index tie-break
    float best = -1e30f; int bidx = 0;
    for (int n = tid; n < SS; n += 1024) {
        float v = cd[IDX(n)].x;
        if (v > best) { best = v; bidx = n; }
    }
    sval[tid] = best; sidx[tid] = bidx;
    __syncthreads();
    for (int s = 512; s > 0; s >>= 1) {
        if (tid < s) {
            float v2 = sval[tid + s]; int i2 = sidx[tid + s];
            if (v2 > sval[tid] || (v2 == sval[tid] && i2 < sidx[tid])) {
                sval[tid] = v2; sidx[tid] = i2;
            }
        }
        __syncthreads();
    }
    if (tid == 0) {
        float ang = (6.28318530717958647692f * (float)sidx[0]) / (float)SS;
        outcos[row] = cosf(ang);
    }
}

// ---------------------------------------------------------------------------
// K3: power spectrum. z = x + i*y (no window); FFT; per rfft bin accumulate
// |xp - tp| and tp in fp64.
// ---------------------------------------------------------------------------
__global__ __launch_bounds__(1024) void k_power(const float* __restrict__ pred,
                                                const float* __restrict__ targ,
                                                const int* __restrict__ ip,
                                                double* __restrict__ onum,
                                                double* __restrict__ oden) {
    __shared__ float2 cd[PADDED];
    __shared__ double dred[1024];
    const int row = blockIdx.x;
    const int tid = threadIdx.x;
    const float* x = pred + (size_t)ip[0] * (size_t)BB * SS + (size_t)row * SS;
    const float* y = targ + (size_t)row * SS;
    for (int n = tid; n < SS; n += 1024) cd[IDX(n)] = make_float2(x[n], y[n]);
    __syncthreads();
    digrev_lds(cd, tid);
    fft4<-1>(cd, tid);
    double anum = 0.0, aden = 0.0;
    for (int k = tid; k <= SS / 2; k += 1024) {
        int m = (SS - k) & (SS - 1);
        float2 Zk = cd[IDX(k)], Zm = cd[IDX(m)];
        float xr = 0.5f * (Zk.x + Zm.x), xi = 0.5f * (Zk.y - Zm.y);
        float yr = 0.5f * (Zk.y + Zm.y), yi = 0.5f * (Zm.x - Zk.x);
        float xp = xr * xr + xi * xi;   // |X|^2
        float tp = yr * yr + yi * yi;   // |Y|^2
        anum += (double)fabsf(xp - tp);
        aden += (double)tp;
    }
    __syncthreads();
    dred[tid] = anum; __syncthreads();
    for (int s = 512; s > 0; s >>= 1) { if (tid < s) dred[tid] += dred[tid + s]; __syncthreads(); }
    if (tid == 0) onum[row] = dred[0];
    __syncthreads();
    dred[tid] = aden; __syncthreads();
    for (int s = 512; s > 0; s >>= 1) { if (tid < s) dred[tid] += dred[tid + s]; __syncthreads(); }
    if (tid == 0) oden[row] = dred[0];
}

// ---------------------------------------------------------------------------
// K4: mutual information per row (10x10 hist, B*S denominator per reference)
// ---------------------------------------------------------------------------
__global__ __launch_bounds__(256) void k_mi(const float* __restrict__ pred,
                                            const float* __restrict__ targ,
                                            const int* __restrict__ ip,
                                            float* __restrict__ onmi) {
    __shared__ float fred[256];
    __shared__ int hist[100];
    __shared__ float hx[10], hy[10];
    __shared__ float bounds[4];  // xmin,xmax,ymin,ymax
    const int row = blockIdx.x;
    const int tid = threadIdx.x;
    const float* x = pred + (size_t)ip[0] * (size_t)BB * SS + (size_t)row * SS;
    const float* y = targ + (size_t)row * SS;
    float xmn = 1e30f, xmx = -1e30f, ymn = 1e30f, ymx = -1e30f;
    for (int n = tid; n < SS; n += 256) {
        float a = x[n], b = y[n];
        xmn = fminf(xmn, a); xmx = fmaxf(xmx, a);
        ymn = fminf(ymn, b); ymx = fmaxf(ymx, b);
    }
    fred[tid] = xmn; __syncthreads();
    for (int s = 128; s > 0; s >>= 1) { if (tid < s) fred[tid] = fminf(fred[tid], fred[tid + s]); __syncthreads(); }
    if (tid == 0) bounds[0] = fred[0]; __syncthreads();
    fred[tid] = xmx; __syncthreads();
    for (int s = 128; s > 0; s >>= 1) { if (tid < s) fred[tid] = fmaxf(fred[tid], fred[tid + s]); __syncthreads(); }
    if (tid == 0) bounds[1] = fred[0]; __syncthreads();
    fred[tid] = ymn; __syncthreads();
    for (int s = 128; s > 0; s >>= 1) { if (tid < s) fred[tid] = fminf(fred[tid], fred[tid + s]); __syncthreads(); }
    if (tid == 0) bounds[2] = fred[0]; __syncthreads();
    fred[tid] = ymx; __syncthreads();
    for (int s = 128; s > 0; s >>= 1) { if (tid < s) fred[tid] = fmaxf(fred[tid], fred[tid + s]); __syncthreads(); }
    if (tid == 0) bounds[3] = fred[0]; __syncthreads();

    float bwx = (bounds[1] - bounds[0]) / 10.0f;
    float bwy = (bounds[3] - bounds[2]) / 10.0f;
    if (tid < 100) hist[tid] = 0;
    __syncthreads();
    for (int n = tid; n < SS; n += 256) {
        float a = x[n], b = y[n];
        int ix = (int)((a - bounds[0]) / bwx); ix = min(max(ix, 0), 9);
        int iy = (int)((b - bounds[2]) / bwy); iy = min(max(iy, 0), 9);
        atomicAdd(&hist[ix * 10 + iy], 1);
    }
    __syncthreads();
    if (tid < 10) {
        int s1 = 0, s2 = 0;
        for (int j = 0; j < 10; ++j) { s1 += hist[tid * 10 + j]; s2 += hist[j * 10 + tid]; }
        hx[tid] = (float)s1; hy[tid] = (float)s2;
    }
    __syncthreads();
    const float denom = 8388608.0f;  // B*S, faithful to the reference
    const float eps = 1e-8f;
    float term = 0.0f;
    if (tid < 100) {
        int i = tid / 10, j = tid % 10;
        float pxy = (float)hist[tid] / denom;
        float px = hx[i] / denom, py = hy[j] / denom;
        term = pxy * logf((pxy + eps) / (px * py + eps));
    }
    fred[tid] = term; __syncthreads();
    for (int s = 128; s > 0; s >>= 1) { if (tid < s) fred[tid] += fred[tid + s]; __syncthreads(); }
    float mi = fred[0]; __syncthreads();

    float e = 0.0f;
    if (tid < 10) { float px = hx[tid] / denom; e = -px * logf(px + eps); }
    fred[tid] = e; __syncthreads();
    for (int s = 128; s > 0; s >>= 1) { if (tid < s) fred[tid] += fred[tid + s]; __syncthreads(); }
    float hxe = fred[0]; __syncthreads();

    e = 0.0f;
    if (tid < 10) { float py = hy[tid] / denom; e = -py * logf(py + eps); }
    fred[tid] = e; __syncthreads();
    for (int s = 128; s > 0; s >>= 1) { if (tid < s) fred[tid] += fred[tid + s]; __syncthreads(); }
    float hye = fred[0]; __syncthreads();

    if (tid == 0) onmi[row] = mi / (0.5f * (hxe + hye));
}

// ---------------------------------------------------------------------------
// K5: final combine (reads epoch on-device; graph-safe)
// ---------------------------------------------------------------------------
__global__ __launch_bounds__(512) void k_combine(const float* __restrict__ wpear,
                                                 const float* __restrict__ wpc,
                                                 const double* __restrict__ wnum,
                                                 const double* __restrict__ wden,
                                                 const float* __restrict__ wnmi,
                                                 const int* __restrict__ ep,
                                                 float* __restrict__ out) {
    __shared__ double dred[512];
    const int tid = threadIdx.x;
    double sums[5];
    double v[5] = {(double)wpear[tid], (double)wpc[tid], wnum[tid], wden[tid], (double)wnmi[tid]};
    for (int q = 0; q < 5; ++q) {
        dred[tid] = v[q]; __syncthreads();
        for (int s = 256; s > 0; s >>= 1) { if (tid < s) dred[tid] += dred[tid + s]; __syncthreads(); }
        sums[q] = dred[0]; __syncthreads();
    }
    if (tid == 0) {
        int epoch = ep[0];
        double loss = sums[0] / 512.0;                 // neg_pearson
        if (epoch >= 400) {
            loss += 1.0 - sums[1] / 512.0;             // phase correlation
            loss += sums[2] / sums[3];                 // power spectrum
        }
        if (epoch >= 700) {
            loss += 1.0 - sums[4] / 512.0;             // mutual information
        }
        out[0] = (float)loss;
    }
}

// ---------------------------------------------------------------------------
extern "C" void kernel_launch(void* const* d_in, const int* in_sizes, int n_in,
                              void* d_out, int out_size, void* d_ws, size_t ws_size,
                              hipStream_t stream) {
    const float* pred = (const float*)d_in[0];   // [2, 512, 16384] f32
    const float* targ = (const float*)d_in[1];   // [512, 16384] f32
    const int* ip = (const int*)d_in[2];         // scalar i
    const int* ep = (const int*)d_in[3];         // scalar epoch
    float* out = (float*)d_out;

    double* wnum = (double*)d_ws;                // [512]
    double* wden = wnum + BB;                    // [512]
    float* wpear = (float*)(wden + BB);          // [512]
    float* wpc = wpear + BB;                     // [512]
    float* wnmi = wpc + BB;                      // [512]

    k_pearson<<<dim3(BB), dim3(256), 0, stream>>>(pred, targ, ip, wpear);
    k_phase<<<dim3(BB), dim3(1024), 0, stream>>>(pred, targ, ip, wpc);
    k_power<<<dim3(BB), dim3(1024), 0, stream>>>(pred, targ, ip, wnum, wden);
    k_mi<<<dim3(BB), dim3(256), 0, stream>>>(pred, targ, ip, wnmi);
    k_combine<<<dim3(1), dim3(512), 0, stream>>>(wpear, wpc, wnum, wden, wnmi, ep, out);
}

// Round 3
// 293.531 us; speedup vs baseline: 2.1277x; 1.1808x over previous
//
#include <hip/hip_runtime.h>
#include <math.h>

#define BB 512
#define SS 16384
#define TPIF 6.28318530717958647692f

// pad so strides {1(contig-16), 4, 64, 1024} across lanes are ~conflict-free (b32)
#define PAD32(i) ((i) + ((i) >> 5) + ((i) >> 10))
#define NPAD 16912   // PAD32(16383)=16909 < 16912

#define K16C0 1.0f
#define K16C1 0.92387953251128674f
#define K16C2 0.70710678118654752f
#define K16C3 0.38268343236508977f
#define K16S0 0.0f
#define K16S1 0.38268343236508977f
#define K16S2 0.70710678118654752f
#define K16S3 0.92387953251128674f

// base-4 digit reversal of 14-bit index (7 digits)
__device__ __forceinline__ int digrev4(int n) {
    unsigned x = __brev((unsigned)n) >> (32 - 14);
    return (int)(((x & 0x1555u) << 1) | ((x >> 1) & 0x1555u));
}

// ---------------------------------------------------------------------------
// Fused DIF pair: stage stride 4Q (block 16Q) then stride Q (block 4Q).
// Thread holds 16 elements z[m] at positions base + m*Q, base = 16*Q*G + p.
// ---------------------------------------------------------------------------
template <int SGN, int Q>
__device__ __forceinline__ void dif_pair(float* zr, float* zi, int p) {
    const float sg = (float)SGN;
    const float kc[4] = {K16C0, K16C1, K16C2, K16C3};
    const float ks[4] = {K16S0, K16S1, K16S2, K16S3};
    {   // stage 1: stride 4 in m, twiddle W_{16Q}^{r*(p+cQ)} on outputs
        const float arev = sg * (float)p * (1.0f / (16.0f * (float)Q));
        const float cb = __builtin_amdgcn_cosf(arev);
        const float sb = __builtin_amdgcn_sinf(arev);
        #pragma unroll
        for (int c = 0; c < 4; ++c) {
            float t0r = zr[c] + zr[c+8],   t0i = zi[c] + zi[c+8];
            float t1r = zr[c] - zr[c+8],   t1i = zi[c] - zi[c+8];
            float t2r = zr[c+4] + zr[c+12], t2i = zi[c+4] + zi[c+12];
            float t3r = zr[c+4] - zr[c+12], t3i = zi[c+4] - zi[c+12];
            float b0r = t0r + t2r, b0i = t0i + t2i;
            float b2r = t0r - t2r, b2i = t0i - t2i;
            float b1r = t1r - sg * t3i, b1i = t1i + sg * t3r;
            float b3r = t1r + sg * t3i, b3i = t1i - sg * t3r;
            float kcc = kc[c], kss = sg * ks[c];
            float w1r = cb * kcc - sb * kss, w1i = sb * kcc + cb * kss;
            float w2r = w1r * w1r - w1i * w1i, w2i = 2.0f * w1r * w1i;
            float w3r = w1r * w2r - w1i * w2i, w3i = w1r * w2i + w1i * w2r;
            zr[c]    = b0r;                   zi[c]    = b0i;
            zr[c+4]  = b1r * w1r - b1i * w1i; zi[c+4]  = b1r * w1i + b1i * w1r;
            zr[c+8]  = b2r * w2r - b2i * w2i; zi[c+8]  = b2r * w2i + b2i * w2r;
            zr[c+12] = b3r * w3r - b3i * w3i; zi[c+12] = b3r * w3i + b3i * w3r;
        }
    }
    {   // stage 2: stride 1 in m, twiddle W_{4Q}^{r*p} on outputs
        const float arev = sg * (float)p * (1.0f / (4.0f * (float)Q));
        const float cb = __builtin_amdgcn_cosf(arev);
        const float sb = __builtin_amdgcn_sinf(arev);
        const float w2r = cb * cb - sb * sb, w2i = 2.0f * cb * sb;
        const float w3r = cb * w2r - sb * w2i, w3i = cb * w2i + sb * w2r;
        #pragma unroll
        for (int r = 0; r < 4; ++r) {
            const int b = 4 * r;
            float t0r = zr[b] + zr[b+2],   t0i = zi[b] + zi[b+2];
            float t1r = zr[b] - zr[b+2],   t1i = zi[b] - zi[b+2];
            float t2r = zr[b+1] + zr[b+3], t2i = zi[b+1] + zi[b+3];
            float t3r = zr[b+1] - zr[b+3], t3i = zi[b+1] - zi[b+3];
            float b0r = t0r + t2r, b0i = t0i + t2i;
            float b2r = t0r - t2r, b2i = t0i - t2i;
            float b1r = t1r - sg * t3i, b1i = t1i + sg * t3r;
            float b3r = t1r + sg * t3i, b3i = t1i - sg * t3r;
            zr[b]   = b0r;                  zi[b]   = b0i;
            zr[b+1] = b1r * cb - b1i * sb;  zi[b+1] = b1r * sb + b1i * cb;
            zr[b+2] = b2r * w2r - b2i * w2i; zi[b+2] = b2r * w2i + b2i * w2r;
            zr[b+3] = b3r * w3r - b3i * w3i; zi[b+3] = b3r * w3i + b3i * w3r;
        }
    }
}

// ---------------------------------------------------------------------------
// Fused DIT pair: stage stride Q (block 4Q) then stride 4Q (block 16Q).
// Twiddles on INPUTS (matches R2's verified DIT butterfly).
// ---------------------------------------------------------------------------
template <int SGN, int Q>
__device__ __forceinline__ void dit_pair(float* zr, float* zi, int p) {
    const float sg = (float)SGN;
    const float kc[4] = {K16C0, K16C1, K16C2, K16C3};
    const float ks[4] = {K16S0, K16S1, K16S2, K16S3};
    {   // stage 1: stride 1 in m, twiddle W_{4Q}^{j*p} on inputs
        const float arev = sg * (float)p * (1.0f / (4.0f * (float)Q));
        const float cb = __builtin_amdgcn_cosf(arev);
        const float sb = __builtin_amdgcn_sinf(arev);
        const float w2r = cb * cb - sb * sb, w2i = 2.0f * cb * sb;
        const float w3r = cb * w2r - sb * w2i, w3i = cb * w2i + sb * w2r;
        #pragma unroll
        for (int k = 0; k < 4; ++k) {
            const int b = 4 * k;
            float a1r = zr[b+1] * cb - zi[b+1] * sb,   a1i = zr[b+1] * sb + zi[b+1] * cb;
            float a2r = zr[b+2] * w2r - zi[b+2] * w2i, a2i = zr[b+2] * w2i + zi[b+2] * w2r;
            float a3r = zr[b+3] * w3r - zi[b+3] * w3i, a3i = zr[b+3] * w3i + zi[b+3] * w3r;
            float t0r = zr[b] + a2r, t0i = zi[b] + a2i;
            float t1r = zr[b] - a2r, t1i = zi[b] - a2i;
            float t2r = a1r + a3r, t2i = a1i + a3i;
            float t3r = a1r - a3r, t3i = a1i - a3i;
            zr[b]   = t0r + t2r;    zi[b]   = t0i + t2i;
            zr[b+2] = t0r - t2r;    zi[b+2] = t0i - t2i;
            zr[b+1] = t1r - sg * t3i; zi[b+1] = t1i + sg * t3r;
            zr[b+3] = t1r + sg * t3i; zi[b+3] = t1i - sg * t3r;
        }
    }
    {   // stage 2: stride 4 in m, twiddle W_{16Q}^{j*(p+rQ)} on inputs
        const float arev = sg * (float)p * (1.0f / (16.0f * (float)Q));
        const float cB = __builtin_amdgcn_cosf(arev);
        const float sB = __builtin_amdgcn_sinf(arev);
        #pragma unroll
        for (int r = 0; r < 4; ++r) {
            float kcc = kc[r], kss = sg * ks[r];
            float w1r = cB * kcc - sB * kss, w1i = sB * kcc + cB * kss;
            float w2r = w1r * w1r - w1i * w1i, w2i = 2.0f * w1r * w1i;
            float w3r = w1r * w2r - w1i * w2i, w3i = w1r * w2i + w1i * w2r;
            float a1r = zr[r+4] * w1r - zi[r+4] * w1i,   a1i = zr[r+4] * w1i + zi[r+4] * w1r;
            float a2r = zr[r+8] * w2r - zi[r+8] * w2i,   a2i = zr[r+8] * w2i + zi[r+8] * w2r;
            float a3r = zr[r+12] * w3r - zi[r+12] * w3i, a3i = zr[r+12] * w3i + zi[r+12] * w3r;
            float t0r = zr[r] + a2r, t0i = zi[r] + a2i;
            float t1r = zr[r] - a2r, t1i = zi[r] - a2i;
            float t2r = a1r + a3r, t2i = a1i + a3i;
            float t3r = a1r - a3r, t3i = a1i - a3i;
            zr[r]    = t0r + t2r;    zi[r]    = t0i + t2i;
            zr[r+8]  = t0r - t2r;    zi[r+8]  = t0i - t2i;
            zr[r+4]  = t1r - sg * t3i; zi[r+4]  = t1i + sg * t3r;
            zr[r+12] = t1r + sg * t3i; zi[r+12] = t1i - sg * t3r;
        }
    }
}

template <int SGN, int LOG2Q>
__device__ __forceinline__ void trip_dif(float* sre, float* sim, int t) {
    constexpr int Q = 1 << LOG2Q;
    const int p = t & (Q - 1);
    const int base = ((t >> LOG2Q) << (LOG2Q + 4)) + p;
    float zr[16], zi[16];
    #pragma unroll
    for (int m = 0; m < 16; ++m) { int ii = PAD32(base + (m << LOG2Q)); zr[m] = sre[ii]; zi[m] = sim[ii]; }
    dif_pair<SGN, Q>(zr, zi, p);
    #pragma unroll
    for (int m = 0; m < 16; ++m) { int ii = PAD32(base + (m << LOG2Q)); sre[ii] = zr[m]; sim[ii] = zi[m]; }
    __syncthreads();
}

template <int SGN, int LOG2Q>
__device__ __forceinline__ void trip_dit(float* sre, float* sim, int t) {
    constexpr int Q = 1 << LOG2Q;
    const int p = t & (Q - 1);
    const int base = ((t >> LOG2Q) << (LOG2Q + 4)) + p;
    float zr[16], zi[16];
    #pragma unroll
    for (int m = 0; m < 16; ++m) { int ii = PAD32(base + (m << LOG2Q)); zr[m] = sre[ii]; zi[m] = sim[ii]; }
    dit_pair<SGN, Q>(zr, zi, p);
    #pragma unroll
    for (int m = 0; m < 16; ++m) { int ii = PAD32(base + (m << LOG2Q)); sre[ii] = zr[m]; sim[ii] = zi[m]; }
    __syncthreads();
}

// single no-twiddle radix-4 stage on contiguous quads (DIF-last / DIT-first)
template <int SGN>
__device__ __forceinline__ void trip_nt(float* sre, float* sim, int t) {
    const float sg = (float)SGN;
    const int base = t << 4;
    float zr[16], zi[16];
    #pragma unroll
    for (int m = 0; m < 16; ++m) { int ii = PAD32(base + m); zr[m] = sre[ii]; zi[m] = sim[ii]; }
    #pragma unroll
    for (int k = 0; k < 4; ++k) {
        int b = 4 * k;
        float t0r = zr[b] + zr[b+2],   t0i = zi[b] + zi[b+2];
        float t1r = zr[b] - zr[b+2],   t1i = zi[b] - zi[b+2];
        float t2r = zr[b+1] + zr[b+3], t2i = zi[b+1] + zi[b+3];
        float t3r = zr[b+1] - zr[b+3], t3i = zi[b+1] - zi[b+3];
        zr[b]   = t0r + t2r;    zi[b]   = t0i + t2i;
        zr[b+2] = t0r - t2r;    zi[b+2] = t0i - t2i;
        zr[b+1] = t1r - sg * t3i; zi[b+1] = t1i + sg * t3r;
        zr[b+3] = t1r + sg * t3i; zi[b+3] = t1i - sg * t3r;
    }
    #pragma unroll
    for (int m = 0; m < 16; ++m) { int ii = PAD32(base + m); sre[ii] = zr[m]; sim[ii] = zi[m]; }
    __syncthreads();
}

// ---------------------------------------------------------------------------
// Mega-kernel: one block per row does Pearson, MI, power-FFT, phase-FFTs.
// ---------------------------------------------------------------------------
__global__ __launch_bounds__(1024) void k_main(const float* __restrict__ pred,
                                               const float* __restrict__ targ,
                                               const int* __restrict__ ip,
                                               float* __restrict__ wpear,
                                               float* __restrict__ wcos,
                                               double* __restrict__ wnum,
                                               double* __restrict__ wden,
                                               float* __restrict__ wnmi) {
    __shared__ float sre[NPAD];
    __shared__ float sim[NPAD];
    __shared__ double dpart[16 * 5];
    __shared__ float fpart[16 * 4];
    __shared__ int   subhist[400];
    __shared__ float hxm[10], hym[10];
    __shared__ float mterm[128];
    __shared__ float sbounds[4];
    __shared__ float svalw[16];
    __shared__ int   sidxw[16];

    const int row = blockIdx.x;
    const int t = threadIdx.x;
    const int w = t >> 6;
    const int lane = t & 63;

    const float* xg = pred + (size_t)ip[0] * (size_t)BB * SS + (size_t)row * SS;
    const float* yg = targ + (size_t)row * SS;

    float xv[16], yv[16];
    #pragma unroll
    for (int m = 0; m < 16; ++m) {
        int n = t + (m << 10);
        xv[m] = xg[n];
        yv[m] = yg[n];
    }

    // ---- Pearson sums (fp64, affine-invariant so raw data ok) + min/max
    {
        double sx = 0, sy = 0, sxy = 0, sxx = 0, syy = 0;
        float xmn = xv[0], xmx = xv[0], ymn = yv[0], ymx = yv[0];
        #pragma unroll
        for (int m = 0; m < 16; ++m) {
            float a = xv[m], b = yv[m];
            sx += (double)a; sy += (double)b;
            sxy += (double)a * (double)b;
            sxx += (double)a * (double)a;
            syy += (double)b * (double)b;
            xmn = fminf(xmn, a); xmx = fmaxf(xmx, a);
            ymn = fminf(ymn, b); ymx = fmaxf(ymx, b);
        }
        #pragma unroll
        for (int o = 32; o > 0; o >>= 1) {
            sx += __shfl_down(sx, o, 64);  sy += __shfl_down(sy, o, 64);
            sxy += __shfl_down(sxy, o, 64);
            sxx += __shfl_down(sxx, o, 64); syy += __shfl_down(syy, o, 64);
            xmn = fminf(xmn, __shfl_down(xmn, o, 64));
            xmx = fmaxf(xmx, __shfl_down(xmx, o, 64));
            ymn = fminf(ymn, __shfl_down(ymn, o, 64));
            ymx = fmaxf(ymx, __shfl_down(ymx, o, 64));
        }
        if (lane == 0) {
            dpart[w*5+0] = sx; dpart[w*5+1] = sy; dpart[w*5+2] = sxy;
            dpart[w*5+3] = sxx; dpart[w*5+4] = syy;
            fpart[w*4+0] = xmn; fpart[w*4+1] = xmx; fpart[w*4+2] = ymn; fpart[w*4+3] = ymx;
        }
    }
    if (t < 400) subhist[t] = 0;
    __syncthreads();
    if (t == 0) {
        double v0=0,v1=0,v2=0,v3=0,v4=0;
        float b0=fpart[0], b1=fpart[1], b2=fpart[2], b3=fpart[3];
        for (int q = 0; q < 16; ++q) {
            v0 += dpart[q*5]; v1 += dpart[q*5+1]; v2 += dpart[q*5+2];
            v3 += dpart[q*5+3]; v4 += dpart[q*5+4];
            b0 = fminf(b0, fpart[q*4]);   b1 = fmaxf(b1, fpart[q*4+1]);
            b2 = fminf(b2, fpart[q*4+2]); b3 = fmaxf(b3, fpart[q*4+3]);
        }
        double N = (double)SS;
        double num = N * v2 - v0 * v1;
        double den = sqrt((N * v3 - v0 * v0) * (N * v4 - v1 * v1));
        wpear[row] = (float)(1.0 - num / den);
        sbounds[0] = b0; sbounds[1] = b1; sbounds[2] = b2; sbounds[3] = b3;
    }
    __syncthreads();

    // ---- MI histogram (4 sub-hists to cut LDS-atomic contention)
    {
        const float x0 = sbounds[0], bwx = (sbounds[1] - x0) / 10.0f;
        const float y0 = sbounds[2], bwy = (sbounds[3] - y0) / 10.0f;
        int* hsub = subhist + ((t >> 6) & 3) * 100;
        #pragma unroll
        for (int m = 0; m < 16; ++m) {
            int ix = (int)((xv[m] - x0) / bwx); ix = min(max(ix, 0), 9);
            int iy = (int)((yv[m] - y0) / bwy); iy = min(max(iy, 0), 9);
            atomicAdd(&hsub[ix * 10 + iy], 1);
        }
    }
    __syncthreads();
    if (t < 100) subhist[t] = subhist[t] + subhist[100+t] + subhist[200+t] + subhist[300+t];
    __syncthreads();
    if (t < 10) {
        int s1 = 0, s2 = 0;
        for (int j = 0; j < 10; ++j) { s1 += subhist[t*10+j]; s2 += subhist[j*10+t]; }
        hxm[t] = (float)s1; hym[t] = (float)s2;
    }
    __syncthreads();
    {
        float term = 0.0f;
        if (t < 100) {
            const float denom = 8388608.0f, eps = 1e-8f;
            float pxy = (float)subhist[t] / denom;
            float px = hxm[t / 10] / denom, py = hym[t % 10] / denom;
            term = pxy * logf((pxy + eps) / (px * py + eps));
        }
        if (t < 128) mterm[t] = (t < 100) ? term : 0.0f;
    }
    __syncthreads();
    if (t == 0) {
        const float denom = 8388608.0f, eps = 1e-8f;
        float mi = 0.0f;
        for (int q = 0; q < 100; ++q) mi += mterm[q];
        float hxe = 0.0f, hye = 0.0f;
        for (int q = 0; q < 10; ++q) {
            float px = hxm[q] / denom, py = hym[q] / denom;
            hxe -= px * logf(px + eps);
            hye -= py * logf(py + eps);
        }
        wnmi[row] = mi / (0.5f * (hxe + hye));
    }

    // ---- FFT1 (power): z = x + i*y, DIF forward; trip A straight from regs
    {
        float zr[16], zi[16];
        #pragma unroll
        for (int m = 0; m < 16; ++m) { zr[m] = xv[m]; zi[m] = yv[m]; }
        dif_pair<-1, 1024>(zr, zi, t);
        #pragma unroll
        for (int m = 0; m < 16; ++m) { int ii = PAD32(t + (m << 10)); sre[ii] = zr[m]; sim[ii] = zi[m]; }
    }
    __syncthreads();
    trip_dif<-1, 6>(sre, sim, t);   // strides 256,64
    trip_dif<-1, 2>(sre, sim, t);   // strides 16,4
    trip_nt<-1>(sre, sim, t);       // stride 1

    // ---- unpack packed-real spectra at rev positions, power sums (fp64)
    {
        double anum = 0.0, aden = 0.0;
        #pragma unroll
        for (int m = 0; m < 8; ++m) {
            int k = t + (m << 10);
            int km = (SS - k) & (SS - 1);
            int q = digrev4(k), q2 = digrev4(km);
            float ar = sre[PAD32(q)],  ai = sim[PAD32(q)];
            float cr = sre[PAD32(q2)], ci = sim[PAD32(q2)];
            float xr = 0.5f * (ar + cr), xi = 0.5f * (ai - ci);
            float yr = 0.5f * (ai + ci), yi = 0.5f * (cr - ar);
            float xp = xr * xr + xi * xi;
            float tp = yr * yr + yi * yi;
            anum += (double)fabsf(xp - tp);
            aden += (double)tp;
        }
        if (t == 0) {   // k = 8192 (self-conjugate)
            int q = digrev4(8192);
            float ar = sre[PAD32(q)], ai = sim[PAD32(q)];
            anum += (double)fabsf(ar * ar - ai * ai);
            aden += (double)(ai * ai);
        }
        #pragma unroll
        for (int o = 32; o > 0; o >>= 1) {
            anum += __shfl_down(anum, o, 64);
            aden += __shfl_down(aden, o, 64);
        }
        if (lane == 0) { dpart[w*2] = anum; dpart[w*2+1] = aden; }
    }
    __syncthreads();
    if (t == 0) {
        double a = 0, b = 0;
        for (int q = 0; q < 16; ++q) { a += dpart[q*2]; b += dpart[q*2+1]; }
        wnum[row] = a; wden[row] = b;
    }

    // ---- FFT2 (phase fwd): z = hann*(x + i*y) from held regs
    {
        float zr[16], zi[16];
        #pragma unroll
        for (int m = 0; m < 16; ++m) {
            int n = t + (m << 10);
            float wv = 0.5f * (1.0f - __builtin_amdgcn_cosf((float)n * (1.0f / 16384.0f)));
            zr[m] = xv[m] * wv; zi[m] = yv[m] * wv;
        }
        dif_pair<-1, 1024>(zr, zi, t);
        #pragma unroll
        for (int m = 0; m < 16; ++m) { int ii = PAD32(t + (m << 10)); sre[ii] = zr[m]; sim[ii] = zi[m]; }
    }
    __syncthreads();
    trip_dif<-1, 6>(sre, sim, t);
    trip_dif<-1, 2>(sre, sim, t);
    trip_nt<-1>(sre, sim, t);

    // ---- unpack + phase-normalize, write C at rev positions (self-contained pairs)
    {
        #pragma unroll
        for (int m = 0; m < 8; ++m) {
            int k = t + (m << 10);
            int km = (SS - k) & (SS - 1);
            int q = digrev4(k), q2 = digrev4(km);
            float ar = sre[PAD32(q)],  ai = sim[PAD32(q)];
            float cr0 = sre[PAD32(q2)], ci0 = sim[PAD32(q2)];
            float xr = 0.5f * (ar + cr0), xi = 0.5f * (ai - ci0);
            float yr = 0.5f * (ai + ci0), yi = 0.5f * (cr0 - ar);
            float cr = xr * yr + xi * yi;
            float ci = xi * yr - xr * yi;
            float mag = sqrtf(cr * cr + ci * ci);
            cr /= mag; ci /= mag;
            sre[PAD32(q)] = cr;  sim[PAD32(q)] = ci;
            sre[PAD32(q2)] = cr; sim[PAD32(q2)] = -ci;
        }
        if (t == 0) {   // k = 8192
            int q = digrev4(8192);
            float ar = sre[PAD32(q)], ai = sim[PAD32(q)];
            float cr = ar * ai;
            cr = cr / fabsf(cr);
            sre[PAD32(q)] = cr; sim[PAD32(q)] = 0.0f;
        }
    }
    __syncthreads();

    // ---- FFT3: inverse DIT (rev input -> natural output), argmax from regs
    trip_nt<1>(sre, sim, t);
    trip_dit<1, 2>(sre, sim, t);
    trip_dit<1, 6>(sre, sim, t);
    {
        float zr[16], zi[16];
        #pragma unroll
        for (int m = 0; m < 16; ++m) { int ii = PAD32(t + (m << 10)); zr[m] = sre[ii]; zi[m] = sim[ii]; }
        dit_pair<1, 1024>(zr, zi, t);
        float bv = zr[0]; int bi = t;
        #pragma unroll
        for (int m = 1; m < 16; ++m) {
            int n = t + (m << 10);
            if (zr[m] > bv) { bv = zr[m]; bi = n; }
        }
        #pragma unroll
        for (int o = 32; o > 0; o >>= 1) {
            float v2 = __shfl_down(bv, o, 64);
            int i2 = __shfl_down(bi, o, 64);
            if (v2 > bv || (v2 == bv && i2 < bi)) { bv = v2; bi = i2; }
        }
        if (lane == 0) { svalw[w] = bv; sidxw[w] = bi; }
    }
    __syncthreads();
    if (t == 0) {
        float bv = svalw[0]; int bi = sidxw[0];
        for (int q = 1; q < 16; ++q) {
            if (svalw[q] > bv || (svalw[q] == bv && sidxw[q] < bi)) { bv = svalw[q]; bi = sidxw[q]; }
        }
        wcos[row] = cosf(TPIF * (float)bi / 16384.0f);
    }
}

// ---------------------------------------------------------------------------
// Final combine (reads epoch on-device; graph-safe)
// ---------------------------------------------------------------------------
__global__ __launch_bounds__(512) void k_combine(const float* __restrict__ wpear,
                                                 const float* __restrict__ wcos,
                                                 const double* __restrict__ wnum,
                                                 const double* __restrict__ wden,
                                                 const float* __restrict__ wnmi,
                                                 const int* __restrict__ ep,
                                                 float* __restrict__ out) {
    __shared__ double dred[512];
    const int tid = threadIdx.x;
    double sums[5];
    double v[5] = {(double)wpear[tid], (double)wcos[tid], wnum[tid], wden[tid], (double)wnmi[tid]};
    for (int q = 0; q < 5; ++q) {
        dred[tid] = v[q]; __syncthreads();
        for (int s = 256; s > 0; s >>= 1) { if (tid < s) dred[tid] += dred[tid + s]; __syncthreads(); }
        sums[q] = dred[0]; __syncthreads();
    }
    if (tid == 0) {
        int epoch = ep[0];
        double loss = sums[0] / 512.0;
        if (epoch >= 400) {
            loss += 1.0 - sums[1] / 512.0;
            loss += sums[2] / sums[3];
        }
        if (epoch >= 700) {
            loss += 1.0 - sums[4] / 512.0;
        }
        out[0] = (float)loss;
    }
}

// ---------------------------------------------------------------------------
extern "C" void kernel_launch(void* const* d_in, const int* in_sizes, int n_in,
                              void* d_out, int out_size, void* d_ws, size_t ws_size,
                              hipStream_t stream) {
    const float* pred = (const float*)d_in[0];   // [2, 512, 16384] f32
    const float* targ = (const float*)d_in[1];   // [512, 16384] f32
    const int* ip = (const int*)d_in[2];         // scalar i
    const int* ep = (const int*)d_in[3];         // scalar epoch
    float* out = (float*)d_out;

    double* wnum = (double*)d_ws;                // [512]
    double* wden = wnum + BB;                    // [512]
    float* wpear = (float*)(wden + BB);          // [512]
    float* wcos = wpear + BB;                    // [512]
    float* wnmi = wcos + BB;                     // [512]

    k_main<<<dim3(BB), dim3(1024), 0, stream>>>(pred, targ, ip, wpear, wcos, wnum, wden, wnmi);
    k_combine<<<dim3(1), dim3(512), 0, stream>>>(wpear, wcos, wnum, wden, wnmi, ep, out);
}

// Round 4
// 289.092 us; speedup vs baseline: 2.1604x; 1.0154x over previous
//
#include <hip/hip_runtime.h>
#include <math.h>

#define BB 512
#define SS 16384
#define TPIF 6.28318530717958647692f

// pad so strides {1(contig-16), 4, 64, 1024} across lanes are ~conflict-free (b32)
#define PAD32(i) ((i) + ((i) >> 5) + ((i) >> 10))
#define NPAD 16912   // PAD32(16383)=16909 < 16912

#define K16C0 1.0f
#define K16C1 0.92387953251128674f
#define K16C2 0.70710678118654752f
#define K16C3 0.38268343236508977f
#define K16S0 0.0f
#define K16S1 0.38268343236508977f
#define K16S2 0.70710678118654752f
#define K16S3 0.92387953251128674f

// base-4 digit reversal of 14-bit index (7 digits)
__device__ __forceinline__ int digrev4(int n) {
    unsigned x = __brev((unsigned)n) >> (32 - 14);
    return (int)(((x & 0x1555u) << 1) | ((x >> 1) & 0x1555u));
}

// ---------------------------------------------------------------------------
// Fused DIF pair: stage stride 4Q (block 16Q) then stride Q (block 4Q).
// Thread holds 16 elements z[m] at positions base + m*Q, base = 16*Q*G + p.
// ---------------------------------------------------------------------------
template <int SGN, int Q>
__device__ __forceinline__ void dif_pair(float* zr, float* zi, int p) {
    const float sg = (float)SGN;
    const float kc[4] = {K16C0, K16C1, K16C2, K16C3};
    const float ks[4] = {K16S0, K16S1, K16S2, K16S3};
    {   // stage 1: stride 4 in m, twiddle W_{16Q}^{r*(p+cQ)} on outputs
        const float arev = sg * (float)p * (1.0f / (16.0f * (float)Q));
        const float cb = __builtin_amdgcn_cosf(arev);
        const float sb = __builtin_amdgcn_sinf(arev);
        #pragma unroll
        for (int c = 0; c < 4; ++c) {
            float t0r = zr[c] + zr[c+8],   t0i = zi[c] + zi[c+8];
            float t1r = zr[c] - zr[c+8],   t1i = zi[c] - zi[c+8];
            float t2r = zr[c+4] + zr[c+12], t2i = zi[c+4] + zi[c+12];
            float t3r = zr[c+4] - zr[c+12], t3i = zi[c+4] - zi[c+12];
            float b0r = t0r + t2r, b0i = t0i + t2i;
            float b2r = t0r - t2r, b2i = t0i - t2i;
            float b1r = t1r - sg * t3i, b1i = t1i + sg * t3r;
            float b3r = t1r + sg * t3i, b3i = t1i - sg * t3r;
            float kcc = kc[c], kss = sg * ks[c];
            float w1r = cb * kcc - sb * kss, w1i = sb * kcc + cb * kss;
            float w2r = w1r * w1r - w1i * w1i, w2i = 2.0f * w1r * w1i;
            float w3r = w1r * w2r - w1i * w2i, w3i = w1r * w2i + w1i * w2r;
            zr[c]    = b0r;                   zi[c]    = b0i;
            zr[c+4]  = b1r * w1r - b1i * w1i; zi[c+4]  = b1r * w1i + b1i * w1r;
            zr[c+8]  = b2r * w2r - b2i * w2i; zi[c+8]  = b2r * w2i + b2i * w2r;
            zr[c+12] = b3r * w3r - b3i * w3i; zi[c+12] = b3r * w3i + b3i * w3r;
        }
    }
    {   // stage 2: stride 1 in m, twiddle W_{4Q}^{r*p} on outputs
        const float arev = sg * (float)p * (1.0f / (4.0f * (float)Q));
        const float cb = __builtin_amdgcn_cosf(arev);
        const float sb = __builtin_amdgcn_sinf(arev);
        const float w2r = cb * cb - sb * sb, w2i = 2.0f * cb * sb;
        const float w3r = cb * w2r - sb * w2i, w3i = cb * w2i + sb * w2r;
        #pragma unroll
        for (int r = 0; r < 4; ++r) {
            const int b = 4 * r;
            float t0r = zr[b] + zr[b+2],   t0i = zi[b] + zi[b+2];
            float t1r = zr[b] - zr[b+2],   t1i = zi[b] - zi[b+2];
            float t2r = zr[b+1] + zr[b+3], t2i = zi[b+1] + zi[b+3];
            float t3r = zr[b+1] - zr[b+3], t3i = zi[b+1] - zi[b+3];
            float b0r = t0r + t2r, b0i = t0i + t2i;
            float b2r = t0r - t2r, b2i = t0i - t2i;
            float b1r = t1r - sg * t3i, b1i = t1i + sg * t3r;
            float b3r = t1r + sg * t3i, b3i = t1i - sg * t3r;
            zr[b]   = b0r;                  zi[b]   = b0i;
            zr[b+1] = b1r * cb - b1i * sb;  zi[b+1] = b1r * sb + b1i * cb;
            zr[b+2] = b2r * w2r - b2i * w2i; zi[b+2] = b2r * w2i + b2i * w2r;
            zr[b+3] = b3r * w3r - b3i * w3i; zi[b+3] = b3r * w3i + b3i * w3r;
        }
    }
}

// ---------------------------------------------------------------------------
// Fused DIT pair: stage stride Q (block 4Q) then stride 4Q (block 16Q).
// Twiddles on INPUTS.
// ---------------------------------------------------------------------------
template <int SGN, int Q>
__device__ __forceinline__ void dit_pair(float* zr, float* zi, int p) {
    const float sg = (float)SGN;
    const float kc[4] = {K16C0, K16C1, K16C2, K16C3};
    const float ks[4] = {K16S0, K16S1, K16S2, K16S3};
    {   // stage 1: stride 1 in m, twiddle W_{4Q}^{j*p} on inputs
        const float arev = sg * (float)p * (1.0f / (4.0f * (float)Q));
        const float cb = __builtin_amdgcn_cosf(arev);
        const float sb = __builtin_amdgcn_sinf(arev);
        const float w2r = cb * cb - sb * sb, w2i = 2.0f * cb * sb;
        const float w3r = cb * w2r - sb * w2i, w3i = cb * w2i + sb * w2r;
        #pragma unroll
        for (int k = 0; k < 4; ++k) {
            const int b = 4 * k;
            float a1r = zr[b+1] * cb - zi[b+1] * sb,   a1i = zr[b+1] * sb + zi[b+1] * cb;
            float a2r = zr[b+2] * w2r - zi[b+2] * w2i, a2i = zr[b+2] * w2i + zi[b+2] * w2r;
            float a3r = zr[b+3] * w3r - zi[b+3] * w3i, a3i = zr[b+3] * w3i + zi[b+3] * w3r;
            float t0r = zr[b] + a2r, t0i = zi[b] + a2i;
            float t1r = zr[b] - a2r, t1i = zi[b] - a2i;
            float t2r = a1r + a3r, t2i = a1i + a3i;
            float t3r = a1r - a3r, t3i = a1i - a3i;
            zr[b]   = t0r + t2r;    zi[b]   = t0i + t2i;
            zr[b+2] = t0r - t2r;    zi[b+2] = t0i - t2i;
            zr[b+1] = t1r - sg * t3i; zi[b+1] = t1i + sg * t3r;
            zr[b+3] = t1r + sg * t3i; zi[b+3] = t1i - sg * t3r;
        }
    }
    {   // stage 2: stride 4 in m, twiddle W_{16Q}^{j*(p+rQ)} on inputs
        const float arev = sg * (float)p * (1.0f / (16.0f * (float)Q));
        const float cB = __builtin_amdgcn_cosf(arev);
        const float sB = __builtin_amdgcn_sinf(arev);
        #pragma unroll
        for (int r = 0; r < 4; ++r) {
            float kcc = kc[r], kss = sg * ks[r];
            float w1r = cB * kcc - sB * kss, w1i = sB * kcc + cB * kss;
            float w2r = w1r * w1r - w1i * w1i, w2i = 2.0f * w1r * w1i;
            float w3r = w1r * w2r - w1i * w2i, w3i = w1r * w2i + w1i * w2r;
            float a1r = zr[r+4] * w1r - zi[r+4] * w1i,   a1i = zr[r+4] * w1i + zi[r+4] * w1r;
            float a2r = zr[r+8] * w2r - zi[r+8] * w2i,   a2i = zr[r+8] * w2i + zi[r+8] * w2r;
            float a3r = zr[r+12] * w3r - zi[r+12] * w3i, a3i = zr[r+12] * w3i + zi[r+12] * w3r;
            float t0r = zr[r] + a2r, t0i = zi[r] + a2i;
            float t1r = zr[r] - a2r, t1i = zi[r] - a2i;
            float t2r = a1r + a3r, t2i = a1i + a3i;
            float t3r = a1r - a3r, t3i = a1i - a3i;
            zr[r]    = t0r + t2r;    zi[r]    = t0i + t2i;
            zr[r+8]  = t0r - t2r;    zi[r+8]  = t0i - t2i;
            zr[r+4]  = t1r - sg * t3i; zi[r+4]  = t1i + sg * t3r;
            zr[r+12] = t1r + sg * t3i; zi[r+12] = t1i - sg * t3r;
        }
    }
}

template <int SGN, int LOG2Q>
__device__ __forceinline__ void trip_dif(float* sre, float* sim, int t) {
    constexpr int Q = 1 << LOG2Q;
    const int p = t & (Q - 1);
    const int base = ((t >> LOG2Q) << (LOG2Q + 4)) + p;
    float zr[16], zi[16];
    #pragma unroll
    for (int m = 0; m < 16; ++m) { int ii = PAD32(base + (m << LOG2Q)); zr[m] = sre[ii]; zi[m] = sim[ii]; }
    dif_pair<SGN, Q>(zr, zi, p);
    #pragma unroll
    for (int m = 0; m < 16; ++m) { int ii = PAD32(base + (m << LOG2Q)); sre[ii] = zr[m]; sim[ii] = zi[m]; }
    __syncthreads();
}

template <int SGN, int LOG2Q>
__device__ __forceinline__ void trip_dit(float* sre, float* sim, int t) {
    constexpr int Q = 1 << LOG2Q;
    const int p = t & (Q - 1);
    const int base = ((t >> LOG2Q) << (LOG2Q + 4)) + p;
    float zr[16], zi[16];
    #pragma unroll
    for (int m = 0; m < 16; ++m) { int ii = PAD32(base + (m << LOG2Q)); zr[m] = sre[ii]; zi[m] = sim[ii]; }
    dit_pair<SGN, Q>(zr, zi, p);
    #pragma unroll
    for (int m = 0; m < 16; ++m) { int ii = PAD32(base + (m << LOG2Q)); sre[ii] = zr[m]; sim[ii] = zi[m]; }
    __syncthreads();
}

// single no-twiddle radix-4 stage on contiguous quads (DIF-last / DIT-first)
template <int SGN>
__device__ __forceinline__ void trip_nt(float* sre, float* sim, int t) {
    const float sg = (float)SGN;
    const int base = t << 4;
    float zr[16], zi[16];
    #pragma unroll
    for (int m = 0; m < 16; ++m) { int ii = PAD32(base + m); zr[m] = sre[ii]; zi[m] = sim[ii]; }
    #pragma unroll
    for (int k = 0; k < 4; ++k) {
        int b = 4 * k;
        float t0r = zr[b] + zr[b+2],   t0i = zi[b] + zi[b+2];
        float t1r = zr[b] - zr[b+2],   t1i = zi[b] - zi[b+2];
        float t2r = zr[b+1] + zr[b+3], t2i = zi[b+1] + zi[b+3];
        float t3r = zr[b+1] - zr[b+3], t3i = zi[b+1] - zi[b+3];
        zr[b]   = t0r + t2r;    zi[b]   = t0i + t2i;
        zr[b+2] = t0r - t2r;    zi[b+2] = t0i - t2i;
        zr[b+1] = t1r - sg * t3i; zi[b+1] = t1i + sg * t3r;
        zr[b+3] = t1r + sg * t3i; zi[b+3] = t1i - sg * t3r;
    }
    #pragma unroll
    for (int m = 0; m < 16; ++m) { int ii = PAD32(base + m); sre[ii] = zr[m]; sim[ii] = zi[m]; }
    __syncthreads();
}

// ---------------------------------------------------------------------------
// Mega-kernel: one block per row does Pearson, MI, power-FFT, phase-FFTs.
// __launch_bounds__(1024, 4): a 16-wave block can only be resident at
// 4 waves/SIMD, which legalizes the 128-VGPR budget -> no scratch spills
// (R3's 64-VGPR default spilled ~580 MB/dispatch to scratch).
// ---------------------------------------------------------------------------
__global__ __launch_bounds__(1024, 4) void k_main(const float* __restrict__ pred,
                                                  const float* __restrict__ targ,
                                                  const int* __restrict__ ip,
                                                  float* __restrict__ wpear,
                                                  float* __restrict__ wcos,
                                                  double* __restrict__ wnum,
                                                  double* __restrict__ wden,
                                                  float* __restrict__ wnmi) {
    __shared__ float sre[NPAD];
    __shared__ float sim[NPAD];
    __shared__ double dpart[16 * 5];
    __shared__ float fpart[16 * 4];
    __shared__ int   subhist[400];
    __shared__ float hxm[10], hym[10];
    __shared__ float mterm[128];
    __shared__ float sbounds[4];
    __shared__ float svalw[16];
    __shared__ int   sidxw[16];

    const int row = blockIdx.x;
    const int t = threadIdx.x;
    const int w = t >> 6;
    const int lane = t & 63;

    const float* xg = pred + (size_t)ip[0] * (size_t)BB * SS + (size_t)row * SS;
    const float* yg = targ + (size_t)row * SS;

    float xv[16], yv[16];
    #pragma unroll
    for (int m = 0; m < 16; ++m) {
        int n = t + (m << 10);
        xv[m] = xg[n];
        yv[m] = yg[n];
    }

    // ---- Pearson sums (fp64, affine-invariant so raw data ok) + min/max
    {
        double sx = 0, sy = 0, sxy = 0, sxx = 0, syy = 0;
        float xmn = xv[0], xmx = xv[0], ymn = yv[0], ymx = yv[0];
        #pragma unroll
        for (int m = 0; m < 16; ++m) {
            float a = xv[m], b = yv[m];
            sx += (double)a; sy += (double)b;
            sxy += (double)a * (double)b;
            sxx += (double)a * (double)a;
            syy += (double)b * (double)b;
            xmn = fminf(xmn, a); xmx = fmaxf(xmx, a);
            ymn = fminf(ymn, b); ymx = fmaxf(ymx, b);
        }
        #pragma unroll
        for (int o = 32; o > 0; o >>= 1) {
            sx += __shfl_down(sx, o, 64);  sy += __shfl_down(sy, o, 64);
            sxy += __shfl_down(sxy, o, 64);
            sxx += __shfl_down(sxx, o, 64); syy += __shfl_down(syy, o, 64);
            xmn = fminf(xmn, __shfl_down(xmn, o, 64));
            xmx = fmaxf(xmx, __shfl_down(xmx, o, 64));
            ymn = fminf(ymn, __shfl_down(ymn, o, 64));
            ymx = fmaxf(ymx, __shfl_down(ymx, o, 64));
        }
        if (lane == 0) {
            dpart[w*5+0] = sx; dpart[w*5+1] = sy; dpart[w*5+2] = sxy;
            dpart[w*5+3] = sxx; dpart[w*5+4] = syy;
            fpart[w*4+0] = xmn; fpart[w*4+1] = xmx; fpart[w*4+2] = ymn; fpart[w*4+3] = ymx;
        }
    }
    if (t < 400) subhist[t] = 0;
    __syncthreads();
    if (t == 0) {
        double v0=0,v1=0,v2=0,v3=0,v4=0;
        float b0=fpart[0], b1=fpart[1], b2=fpart[2], b3=fpart[3];
        for (int q = 0; q < 16; ++q) {
            v0 += dpart[q*5]; v1 += dpart[q*5+1]; v2 += dpart[q*5+2];
            v3 += dpart[q*5+3]; v4 += dpart[q*5+4];
            b0 = fminf(b0, fpart[q*4]);   b1 = fmaxf(b1, fpart[q*4+1]);
            b2 = fminf(b2, fpart[q*4+2]); b3 = fmaxf(b3, fpart[q*4+3]);
        }
        double N = (double)SS;
        double num = N * v2 - v0 * v1;
        double den = sqrt((N * v3 - v0 * v0) * (N * v4 - v1 * v1));
        wpear[row] = (float)(1.0 - num / den);
        sbounds[0] = b0; sbounds[1] = b1; sbounds[2] = b2; sbounds[3] = b3;
    }
    __syncthreads();

    // ---- MI histogram (4 sub-hists to cut LDS-atomic contention)
    {
        const float x0 = sbounds[0], bwx = (sbounds[1] - x0) / 10.0f;
        const float y0 = sbounds[2], bwy = (sbounds[3] - y0) / 10.0f;
        int* hsub = subhist + ((t >> 6) & 3) * 100;
        #pragma unroll
        for (int m = 0; m < 16; ++m) {
            int ix = (int)((xv[m] - x0) / bwx); ix = min(max(ix, 0), 9);
            int iy = (int)((yv[m] - y0) / bwy); iy = min(max(iy, 0), 9);
            atomicAdd(&hsub[ix * 10 + iy], 1);
        }
    }
    __syncthreads();
    if (t < 100) subhist[t] = subhist[t] + subhist[100+t] + subhist[200+t] + subhist[300+t];
    __syncthreads();
    if (t < 10) {
        int s1 = 0, s2 = 0;
        for (int j = 0; j < 10; ++j) { s1 += subhist[t*10+j]; s2 += subhist[j*10+t]; }
        hxm[t] = (float)s1; hym[t] = (float)s2;
    }
    __syncthreads();
    {
        float term = 0.0f;
        if (t < 100) {
            const float denom = 8388608.0f, eps = 1e-8f;
            float pxy = (float)subhist[t] / denom;
            float px = hxm[t / 10] / denom, py = hym[t % 10] / denom;
            term = pxy * logf((pxy + eps) / (px * py + eps));
        }
        if (t < 128) mterm[t] = (t < 100) ? term : 0.0f;
    }
    __syncthreads();
    if (t == 0) {
        const float denom = 8388608.0f, eps = 1e-8f;
        float mi = 0.0f;
        for (int q = 0; q < 100; ++q) mi += mterm[q];
        float hxe = 0.0f, hye = 0.0f;
        for (int q = 0; q < 10; ++q) {
            float px = hxm[q] / denom, py = hym[q] / denom;
            hxe -= px * logf(px + eps);
            hye -= py * logf(py + eps);
        }
        wnmi[row] = mi / (0.5f * (hxe + hye));
    }

    // ---- FFT1 (power): z = x + i*y, DIF forward; trip A straight from regs
    {
        float zr[16], zi[16];
        #pragma unroll
        for (int m = 0; m < 16; ++m) { zr[m] = xv[m]; zi[m] = yv[m]; }
        dif_pair<-1, 1024>(zr, zi, t);
        #pragma unroll
        for (int m = 0; m < 16; ++m) { int ii = PAD32(t + (m << 10)); sre[ii] = zr[m]; sim[ii] = zi[m]; }
    }
    __syncthreads();
    trip_dif<-1, 6>(sre, sim, t);   // strides 256,64
    trip_dif<-1, 2>(sre, sim, t);   // strides 16,4
    trip_nt<-1>(sre, sim, t);       // stride 1

    // ---- unpack packed-real spectra at rev positions, power sums (fp64)
    {
        double anum = 0.0, aden = 0.0;
        #pragma unroll
        for (int m = 0; m < 8; ++m) {
            int k = t + (m << 10);
            int km = (SS - k) & (SS - 1);
            int q = digrev4(k), q2 = digrev4(km);
            float ar = sre[PAD32(q)],  ai = sim[PAD32(q)];
            float cr = sre[PAD32(q2)], ci = sim[PAD32(q2)];
            float xr = 0.5f * (ar + cr), xi = 0.5f * (ai - ci);
            float yr = 0.5f * (ai + ci), yi = 0.5f * (cr - ar);
            float xp = xr * xr + xi * xi;
            float tp = yr * yr + yi * yi;
            anum += (double)fabsf(xp - tp);
            aden += (double)tp;
        }
        if (t == 0) {   // k = 8192 (self-conjugate)
            int q = digrev4(8192);
            float ar = sre[PAD32(q)], ai = sim[PAD32(q)];
            anum += (double)fabsf(ar * ar - ai * ai);
            aden += (double)(ai * ai);
        }
        #pragma unroll
        for (int o = 32; o > 0; o >>= 1) {
            anum += __shfl_down(anum, o, 64);
            aden += __shfl_down(aden, o, 64);
        }
        if (lane == 0) { dpart[w*2] = anum; dpart[w*2+1] = aden; }
    }
    __syncthreads();
    if (t == 0) {
        double a = 0, b = 0;
        for (int q = 0; q < 16; ++q) { a += dpart[q*2]; b += dpart[q*2+1]; }
        wnum[row] = a; wden[row] = b;
    }

    // ---- FFT2 (phase fwd): z = hann*(x + i*y) from held regs
    {
        float zr[16], zi[16];
        #pragma unroll
        for (int m = 0; m < 16; ++m) {
            int n = t + (m << 10);
            float wv = 0.5f * (1.0f - __builtin_amdgcn_cosf((float)n * (1.0f / 16384.0f)));
            zr[m] = xv[m] * wv; zi[m] = yv[m] * wv;
        }
        dif_pair<-1, 1024>(zr, zi, t);
        #pragma unroll
        for (int m = 0; m < 16; ++m) { int ii = PAD32(t + (m << 10)); sre[ii] = zr[m]; sim[ii] = zi[m]; }
    }
    __syncthreads();
    trip_dif<-1, 6>(sre, sim, t);
    trip_dif<-1, 2>(sre, sim, t);
    trip_nt<-1>(sre, sim, t);

    // ---- unpack + phase-normalize, write C at rev positions (self-contained pairs)
    {
        #pragma unroll
        for (int m = 0; m < 8; ++m) {
            int k = t + (m << 10);
            int km = (SS - k) & (SS - 1);
            int q = digrev4(k), q2 = digrev4(km);
            float ar = sre[PAD32(q)],  ai = sim[PAD32(q)];
            float cr0 = sre[PAD32(q2)], ci0 = sim[PAD32(q2)];
            float xr = 0.5f * (ar + cr0), xi = 0.5f * (ai - ci0);
            float yr = 0.5f * (ai + ci0), yi = 0.5f * (cr0 - ar);
            float cr = xr * yr + xi * yi;
            float ci = xi * yr - xr * yi;
            float mag = sqrtf(cr * cr + ci * ci);
            cr /= mag; ci /= mag;
            sre[PAD32(q)] = cr;  sim[PAD32(q)] = ci;
            sre[PAD32(q2)] = cr; sim[PAD32(q2)] = -ci;
        }
        if (t == 0) {   // k = 8192
            int q = digrev4(8192);
            float ar = sre[PAD32(q)], ai = sim[PAD32(q)];
            float cr = ar * ai;
            cr = cr / fabsf(cr);
            sre[PAD32(q)] = cr; sim[PAD32(q)] = 0.0f;
        }
    }
    __syncthreads();

    // ---- FFT3: inverse DIT (rev input -> natural output), argmax from regs
    trip_nt<1>(sre, sim, t);
    trip_dit<1, 2>(sre, sim, t);
    trip_dit<1, 6>(sre, sim, t);
    {
        float zr[16], zi[16];
        #pragma unroll
        for (int m = 0; m < 16; ++m) { int ii = PAD32(t + (m << 10)); zr[m] = sre[ii]; zi[m] = sim[ii]; }
        dit_pair<1, 1024>(zr, zi, t);
        float bv = zr[0]; int bi = t;
        #pragma unroll
        for (int m = 1; m < 16; ++m) {
            int n = t + (m << 10);
            if (zr[m] > bv) { bv = zr[m]; bi = n; }
        }
        #pragma unroll
        for (int o = 32; o > 0; o >>= 1) {
            float v2 = __shfl_down(bv, o, 64);
            int i2 = __shfl_down(bi, o, 64);
            if (v2 > bv || (v2 == bv && i2 < bi)) { bv = v2; bi = i2; }
        }
        if (lane == 0) { svalw[w] = bv; sidxw[w] = bi; }
    }
    __syncthreads();
    if (t == 0) {
        float bv = svalw[0]; int bi = sidxw[0];
        for (int q = 1; q < 16; ++q) {
            if (svalw[q] > bv || (svalw[q] == bv && sidxw[q] < bi)) { bv = svalw[q]; bi = sidxw[q]; }
        }
        wcos[row] = cosf(TPIF * (float)bi / 16384.0f);
    }
}

// ---------------------------------------------------------------------------
// Final combine (reads epoch on-device; graph-safe). Wave-shuffle reductions.
// ---------------------------------------------------------------------------
__global__ __launch_bounds__(512) void k_combine(const float* __restrict__ wpear,
                                                 const float* __restrict__ wcos,
                                                 const double* __restrict__ wnum,
                                                 const double* __restrict__ wden,
                                                 const float* __restrict__ wnmi,
                                                 const int* __restrict__ ep,
                                                 float* __restrict__ out) {
    __shared__ double dp[8 * 5];
    const int tid = threadIdx.x;
    const int w = tid >> 6, lane = tid & 63;
    double v0 = (double)wpear[tid], v1 = (double)wcos[tid];
    double v2 = wnum[tid], v3 = wden[tid], v4 = (double)wnmi[tid];
    #pragma unroll
    for (int o = 32; o > 0; o >>= 1) {
        v0 += __shfl_down(v0, o, 64); v1 += __shfl_down(v1, o, 64);
        v2 += __shfl_down(v2, o, 64); v3 += __shfl_down(v3, o, 64);
        v4 += __shfl_down(v4, o, 64);
    }
    if (lane == 0) {
        dp[w*5+0] = v0; dp[w*5+1] = v1; dp[w*5+2] = v2; dp[w*5+3] = v3; dp[w*5+4] = v4;
    }
    __syncthreads();
    if (tid == 0) {
        double s0=0,s1=0,s2=0,s3=0,s4=0;
        for (int q = 0; q < 8; ++q) {
            s0 += dp[q*5]; s1 += dp[q*5+1]; s2 += dp[q*5+2]; s3 += dp[q*5+3]; s4 += dp[q*5+4];
        }
        int epoch = ep[0];
        double loss = s0 / 512.0;
        if (epoch >= 400) {
            loss += 1.0 - s1 / 512.0;
            loss += s2 / s3;
        }
        if (epoch >= 700) {
            loss += 1.0 - s4 / 512.0;
        }
        out[0] = (float)loss;
    }
}

// ---------------------------------------------------------------------------
extern "C" void kernel_launch(void* const* d_in, const int* in_sizes, int n_in,
                              void* d_out, int out_size, void* d_ws, size_t ws_size,
                              hipStream_t stream) {
    const float* pred = (const float*)d_in[0];   // [2, 512, 16384] f32
    const float* targ = (const float*)d_in[1];   // [512, 16384] f32
    const int* ip = (const int*)d_in[2];         // scalar i
    const int* ep = (const int*)d_in[3];         // scalar epoch
    float* out = (float*)d_out;

    double* wnum = (double*)d_ws;                // [512]
    double* wden = wnum + BB;                    // [512]
    float* wpear = (float*)(wden + BB);          // [512]
    float* wcos = wpear + BB;                    // [512]
    float* wnmi = wcos + BB;                     // [512]

    k_main<<<dim3(BB), dim3(1024), 0, stream>>>(pred, targ, ip, wpear, wcos, wnum, wden, wnmi);
    k_combine<<<dim3(1), dim3(512), 0, stream>>>(wpear, wcos, wnum, wden, wnmi, ep, out);
}